// Round 10
// baseline (834.828 us; speedup 1.0000x reference)
//
#include <hip/hip_runtime.h>

typedef unsigned short ushort_t;
typedef unsigned int   u32;
typedef __attribute__((ext_vector_type(8))) short bf16x8;
typedef __attribute__((ext_vector_type(4))) float f32x4;

#define NNODES 100000
#define DIM    256
#define NEDGE  300000
#define KSTEPS 16           // BK = 32 over virtual K = [agg | xin] = 512
#define BROWS  512          // rows per block (8 waves x 64 rows)
#define CCOLS  64           // cols per block (4 col-blocks cover DIM=256)
#define CREG   65536        // ushorts per col-block B region: 64 cols x 512 K x 2 planes
// B region layout (ushorts): ks*4096 + plane*2048 + ct*512 + q*128 + nn*8 + j
//   (ct: 4 tiles of 16 cols; lane-contiguous: ct*512 + lane*8 per fragment)
// A tensors are split-bf16 planes: row = [256 hi ushorts | 256 lo ushorts]
#define MFMA16 __builtin_amdgcn_mfma_f32_16x16x32_bf16

// ================= CSR build (counting sort by dst) =================

__global__ void count_kernel(const int* __restrict__ dst, int* __restrict__ cnt, int E) {
    int e = blockIdx.x * blockDim.x + threadIdx.x;
    if (e < E) atomicAdd(&cnt[dst[e]], 1);
}

__global__ void scan1(const int* __restrict__ cnt, int* __restrict__ partial, int n) {
    __shared__ int s[256];
    int i = blockIdx.x * 256 + threadIdx.x;
    s[threadIdx.x] = (i < n) ? cnt[i] : 0;
    __syncthreads();
    for (int off = 128; off > 0; off >>= 1) {
        if (threadIdx.x < off) s[threadIdx.x] += s[threadIdx.x + off];
        __syncthreads();
    }
    if (threadIdx.x == 0) partial[blockIdx.x] = s[0];
}

__global__ void scan2(int* __restrict__ partial, int nb) {
    __shared__ int s[512];
    int t = threadIdx.x;
    int orig = (t < nb) ? partial[t] : 0;
    s[t] = orig;
    __syncthreads();
    for (int off = 1; off < 512; off <<= 1) {
        int v = (t >= off) ? s[t - off] : 0;
        __syncthreads();
        s[t] += v;
        __syncthreads();
    }
    if (t < nb) partial[t] = s[t] - orig;  // exclusive
}

__global__ void scan3(const int* __restrict__ cnt, const int* __restrict__ partial,
                      int* __restrict__ row_start, int n) {
    __shared__ int s[256];
    int i = blockIdx.x * 256 + threadIdx.x;
    int v = (i < n) ? cnt[i] : 0;
    s[threadIdx.x] = v;
    __syncthreads();
    for (int off = 1; off < 256; off <<= 1) {
        int t = (threadIdx.x >= off) ? s[threadIdx.x - off] : 0;
        __syncthreads();
        s[threadIdx.x] += t;
        __syncthreads();
    }
    if (i < n) row_start[i] = partial[blockIdx.x] + s[threadIdx.x] - v;
}

__global__ void fill_csr(const int* __restrict__ src, const int* __restrict__ dst,
                         const int* __restrict__ row_start, int* __restrict__ cursor,
                         int* __restrict__ esrc, int E) {
    int e = blockIdx.x * blockDim.x + threadIdx.x;
    if (e < E) {
        int d = dst[e];
        int pos = row_start[d] + atomicAdd(&cursor[d], 1);
        esrc[pos] = src[e];
    }
}

// ================= split helpers =================

__device__ __forceinline__ float bfhi(unsigned u) { return __uint_as_float(u << 16); }
__device__ __forceinline__ float bflo(unsigned u) { return __uint_as_float(u & 0xFFFF0000u); }

// split 4 floats -> packed hi uint2 + lo uint2 (truncating split)
__device__ __forceinline__ void split4pack(float v0, float v1, float v2, float v3,
                                           uint2& hi, uint2& lo) {
    unsigned u0 = __float_as_uint(v0), u1 = __float_as_uint(v1);
    unsigned u2 = __float_as_uint(v2), u3 = __float_as_uint(v3);
    hi.x = (u0 >> 16) | (u1 & 0xFFFF0000u);
    hi.y = (u2 >> 16) | (u3 & 0xFFFF0000u);
    unsigned w0 = __float_as_uint(v0 - bflo(u0)), w1 = __float_as_uint(v1 - bflo(u1));
    unsigned w2 = __float_as_uint(v2 - bflo(u2)), w3 = __float_as_uint(v3 - bflo(u3));
    lo.x = (w0 >> 16) | (w1 & 0xFFFF0000u);
    lo.y = (w2 >> 16) | (w3 & 0xFFFF0000u);
}

// ================= x -> split-plane form (one-time) =================
__global__ __launch_bounds__(256) void split_x(const float* __restrict__ x,
                                               ushort_t* __restrict__ x2) {
    int idx = blockIdx.x * 256 + threadIdx.x;      // node*64 + lane
    if (idx >= NNODES * 64) return;
    int node = idx >> 6, lane = idx & 63;
    float4 v = ((const float4*)(x + (size_t)node * DIM))[lane];
    uint2 hi, lo;
    split4pack(v.x, v.y, v.z, v.w, hi, lo);
    *(uint2*)(x2 + (size_t)node * 512 + lane * 4)       = hi;
    *(uint2*)(x2 + (size_t)node * 512 + 256 + lane * 4) = lo;
}

// ================= aggregation: one wave per node, split-plane in/out =================
__global__ __launch_bounds__(256) void aggregate2(
    const int* __restrict__ esrc, const int* __restrict__ row_start,
    const int* __restrict__ cnt, const ushort_t* __restrict__ x2,
    ushort_t* __restrict__ agg2)
{
    int node = (blockIdx.x * blockDim.x + threadIdx.x) >> 6;
    int lane = threadIdx.x & 63;
    if (node >= NNODES) return;
    int start = row_start[node];
    int c = cnt[node];
    float a0 = 0.f, a1 = 0.f, a2 = 0.f, a3 = 0.f;
    for (int i = 0; i < c; i++) {
        int s = esrc[start + i];
        const uint2 h = *(const uint2*)(x2 + (size_t)s * 512 + lane * 4);
        const uint2 l = *(const uint2*)(x2 + (size_t)s * 512 + 256 + lane * 4);
        a0 += bfhi(h.x) + bfhi(l.x);
        a1 += bflo(h.x) + bflo(l.x);
        a2 += bfhi(h.y) + bfhi(l.y);
        a3 += bflo(h.y) + bflo(l.y);
    }
    float inv = (c > 0) ? 1.0f / (float)c : 0.0f;
    uint2 hi, lo;
    split4pack(a0 * inv, a1 * inv, a2 * inv, a3 * inv, hi, lo);
    *(uint2*)(agg2 + (size_t)node * 512 + lane * 4)       = hi;
    *(uint2*)(agg2 + (size_t)node * 512 + 256 + lane * 4) = lo;
}

// ========== weight split into per-col-block full-K MFMA-fragment regions ==========
__global__ void conv_weights(const float* __restrict__ Wl, const float* __restrict__ Wr,
                             ushort_t* __restrict__ Bsw) {
    int idx = blockIdx.x * 256 + threadIdx.x;      // n*512 + k
    if (idx >= 256 * 512) return;
    int n = idx >> 9, k = idx & 511;
    float v = (k < DIM) ? Wl[n * DIM + k] : Wr[n * DIM + (k - DIM)];
    unsigned u = __float_as_uint(v);
    float lo = v - bflo(u);
    int cb = n >> 6, ct = (n >> 4) & 3, nn = n & 15;
    int ks = k >> 5, q = (k >> 3) & 3, j = k & 7;
    int base = cb * CREG + ks * 4096 + ct * 512 + q * 128 + nn * 8 + j;
    Bsw[base]        = (ushort_t)(u >> 16);                      // hi plane
    Bsw[base + 2048] = (ushort_t)(__float_as_uint(lo) >> 16);    // lo plane
}

// ================= MFMA GEMM: out = [agg|xin] @ B^T + bias (split-bf16, fp32 acc) ===============
// STAGE-ONCE / BARRIER-FREE K-LOOP. Six schedule variants with per-k-step LDS staging all
// plateaued at 128-137 us: the k-loop's stage->publish->barrier->read critical path is
// structure-invariant (~6.8K cy/step vs ~1.5K of throughput work). Here the block's entire
// B slice (64 cols x full K=512, hi+lo planes = 128 KB) is DMA'd to LDS once in the
// prologue; after ONE __syncthreads the 16 k-steps are pure {A-load, ds_read, MFMA} with no
// barriers, no staging, no inline asm — 8 independent waves, compiler-scheduled straight
// line (fully unrolled). Grid = row-blocks x 4 col-blocks; buffers are rotated by the
// launcher so output never aliases any GEMM input (no in-place, no epilogue barrier).
// Per wave: 64 rows (4 rt) x 64 cols (4 ct); acc 4x4 f32x4 = 64 VGPR; A-frags 2-deep
// (64 VGPR) => fits the 256-VGPR budget at 2 waves/SIMD (1 block/CU, LDS-capped).
__global__ __launch_bounds__(512, 2) void sage_gemm_mfma(
    const ushort_t* __restrict__ aggp, const ushort_t* __restrict__ xinp,
    const ushort_t* __restrict__ Bsw, const float* __restrict__ bias,
    void* __restrict__ outp, int M, int out_split)
{
    __shared__ __align__(16) ushort_t Bs[CREG];   // 128 KB: full-K B for this col-block

    const int tid  = threadIdx.x;
    const int lane = tid & 63;
    const int wave = tid >> 6;          // 0..7
    const int lrow = lane & 15;
    const int quad = lane >> 4;

    const int rb = blockIdx.x >> 2;     // row-block
    const int cb = blockIdx.x & 3;      // col-block (64 cols)

    const int rowbase = rb * BROWS + wave * 64;
    int r[4];
    #pragma unroll
    for (int rt = 0; rt < 4; rt++)
        r[rt] = min(rowbase + rt * 16 + lrow, M - 1);   // clamped reads (tail)
    const int kq = quad * 8;

    // ---- prologue: DMA the whole 128 KB B region to LDS (8192 x 16B chunks, 16/thread) ----
    const ushort_t* breg = Bsw + (size_t)cb * CREG;
    #pragma unroll
    for (int i = 0; i < 16; i++) {
        const int c      = tid + i * 512;        // per-lane 16B chunk index (lane-linear)
        const int cbase  = wave * 64 + i * 512;  // wave-uniform base chunk
        __builtin_amdgcn_global_load_lds(
            (const __attribute__((address_space(1))) u32*)(breg + (size_t)c * 8),
            (__attribute__((address_space(3))) u32*)(Bs + cbase * 8),
            16, 0, 0);
    }

    f32x4 acc[4][4];
    #pragma unroll
    for (int i = 0; i < 4; i++)
        #pragma unroll
        for (int j = 0; j < 4; j++)
            acc[i][j] = (f32x4){0.f, 0.f, 0.f, 0.f};

    // A-frag prefetch, 2-deep: fr[p][2*rt] = hi, fr[p][2*rt+1] = lo
    bf16x8 fr[2][8];
    #pragma unroll
    for (int rt = 0; rt < 4; rt++) {
        const ushort_t* p = aggp + (size_t)r[rt] * 512 + kq;          // ks=0
        fr[0][2 * rt]     = *(const bf16x8*)(p);
        fr[0][2 * rt + 1] = *(const bf16x8*)(p + 256);
        const ushort_t* q2 = aggp + (size_t)r[rt] * 512 + 32 + kq;    // ks=1
        fr[1][2 * rt]     = *(const bf16x8*)(q2);
        fr[1][2 * rt + 1] = *(const bf16x8*)(q2 + 256);
    }

    __syncthreads();   // one-time: drains B DMAs (and A prefetch), publishes LDS

    #pragma unroll
    for (int ks = 0; ks < KSTEPS; ks++) {
        const ushort_t* bp = Bs + ks * 4096 + lane * 8;
        #pragma unroll
        for (int ct = 0; ct < 4; ct++) {
            const bf16x8 bh = *(const bf16x8*)(bp + ct * 512);
            const bf16x8 bl = *(const bf16x8*)(bp + 2048 + ct * 512);
            #pragma unroll
            for (int rt = 0; rt < 4; rt++) {
                acc[rt][ct] = MFMA16(fr[ks & 1][2 * rt],     bh, acc[rt][ct], 0, 0, 0);
                acc[rt][ct] = MFMA16(fr[ks & 1][2 * rt + 1], bh, acc[rt][ct], 0, 0, 0);
                acc[rt][ct] = MFMA16(fr[ks & 1][2 * rt],     bl, acc[rt][ct], 0, 0, 0);
            }
        }
        // A[ks+2] overwrites fr[ks&1] after its last MFMA use (WAR-ordered by compiler)
        if (ks + 2 < KSTEPS) {
            const int k2 = ks + 2;
            const ushort_t* ab = (k2 < 8) ? aggp : xinp;
            const int kk = (k2 & 7) * 32 + kq;
            #pragma unroll
            for (int rt = 0; rt < 4; rt++) {
                const ushort_t* p = ab + (size_t)r[rt] * 512 + kk;
                fr[ks & 1][2 * rt]     = *(const bf16x8*)(p);
                fr[ks & 1][2 * rt + 1] = *(const bf16x8*)(p + 256);
            }
        }
    }

    // ---- epilogue (no barrier needed: output buffer never aliases any GEMM input) ----
    // C layout: col=lane&15, row=quad*4+reg
    #pragma unroll
    for (int rt = 0; rt < 4; rt++) {
        #pragma unroll
        for (int rr = 0; rr < 4; rr++) {
            const int row = rowbase + rt * 16 + quad * 4 + rr;
            if (row < M) {
                if (out_split) {
                    ushort_t* orow = (ushort_t*)outp + (size_t)row * 512;
                    #pragma unroll
                    for (int ct = 0; ct < 4; ct++) {
                        const int col = cb * CCOLS + ct * 16 + lrow;
                        float v = fmaxf(acc[rt][ct][rr] + bias[col], 0.f);
                        unsigned u = __float_as_uint(v);
                        float lo = v - bflo(u);
                        orow[col]       = (ushort_t)(u >> 16);
                        orow[col + 256] = (ushort_t)(__float_as_uint(lo) >> 16);
                    }
                } else {
                    float* orow = (float*)outp + (size_t)row * DIM;
                    #pragma unroll
                    for (int ct = 0; ct < 4; ct++) {
                        const int col = cb * CCOLS + ct * 16 + lrow;
                        orow[col] = acc[rt][ct][rr] + bias[col];
                    }
                }
            }
        }
    }
}

extern "C" void kernel_launch(void* const* d_in, const int* in_sizes, int n_in,
                              void* d_out, int out_size, void* d_ws, size_t ws_size,
                              hipStream_t stream) {
    const int*   edge = (const int*)d_in[0];
    const int*   src  = edge;
    const int*   dst  = edge + NEDGE;
    const float* x    = (const float*)d_in[1];
    const float* Wl1  = (const float*)d_in[2];
    const float* Wr1  = (const float*)d_in[3];
    const float* b1   = (const float*)d_in[4];
    const float* Wl2  = (const float*)d_in[5];
    const float* Wr2  = (const float*)d_in[6];
    const float* b2   = (const float*)d_in[7];
    const float* Wl3  = (const float*)d_in[8];
    const float* Wr3  = (const float*)d_in[9];
    const float* b3   = (const float*)d_in[10];

    const size_t feat = (size_t)NNODES * 512;   // ushorts per split-plane tensor (102.4 MB)

    // Three-buffer rotation (no GEMM writes alias any GEMM reads):
    //   R1, R2 in workspace; R3 = d_out region (scratch until layer 3 writes f32 there).
    ushort_t* R1        = (ushort_t*)d_ws;
    ushort_t* R2        = R1 + feat;
    int*      cnt       = (int*)(R2 + feat);
    int*      row_start = cnt + NNODES;
    int*      cursor    = row_start + NNODES;
    int*      partial   = cursor + NNODES;            // 512
    int*      esrc      = partial + 512;              // NEDGE
    ushort_t* Bsw       = (ushort_t*)(esrc + NEDGE);  // 4*CREG ushorts (512 KB)
    ushort_t* R3        = (ushort_t*)d_out;

    const int nScanBlocks = (NNODES + 255) / 256;

    // ---- CSR build (edge structure shared by all 3 layers) ----
    hipMemsetAsync(cnt, 0, NNODES * sizeof(int), stream);
    hipMemsetAsync(cursor, 0, NNODES * sizeof(int), stream);
    count_kernel<<<(NEDGE + 255) / 256, 256, 0, stream>>>(dst, cnt, NEDGE);
    scan1<<<nScanBlocks, 256, 0, stream>>>(cnt, partial, NNODES);
    scan2<<<1, 512, 0, stream>>>(partial, nScanBlocks);
    scan3<<<nScanBlocks, 256, 0, stream>>>(cnt, partial, row_start, NNODES);
    fill_csr<<<(NEDGE + 255) / 256, 256, 0, stream>>>(src, dst, row_start, cursor, esrc, NEDGE);

    split_x<<<(NNODES * 64 + 255) / 256, 256, 0, stream>>>(x, R1);

    const int aggBlocks  = (NNODES * 64 + 255) / 256;
    const int gemmBlocks = ((NNODES + BROWS - 1) / BROWS) * 4;   // 196 row-blocks x 4 col-blocks
    const int convBlocks = (256 * 512 + 255) / 256;

    // ---- layer 1: agg(R1)->R2; out = [R2|R1] @ B1 -> R3 (split) ----
    conv_weights<<<convBlocks, 256, 0, stream>>>(Wl1, Wr1, Bsw);
    aggregate2<<<aggBlocks, 256, 0, stream>>>(esrc, row_start, cnt, R1, R2);
    sage_gemm_mfma<<<gemmBlocks, 512, 0, stream>>>(R2, R1, Bsw, b1, (void*)R3, NNODES, 1);

    // ---- layer 2: agg(R3)->R1; out = [R1|R3] @ B2 -> R2 (split) ----
    conv_weights<<<convBlocks, 256, 0, stream>>>(Wl2, Wr2, Bsw);
    aggregate2<<<aggBlocks, 256, 0, stream>>>(esrc, row_start, cnt, R3, R1);
    sage_gemm_mfma<<<gemmBlocks, 512, 0, stream>>>(R1, R3, Bsw, b2, (void*)R2, NNODES, 1);

    // ---- layer 3: agg(R2)->R1; out = [R1|R2] @ B3 -> d_out (f32) ----
    conv_weights<<<convBlocks, 256, 0, stream>>>(Wl3, Wr3, Bsw);
    aggregate2<<<aggBlocks, 256, 0, stream>>>(esrc, row_start, cnt, R2, R1);
    sage_gemm_mfma<<<gemmBlocks, 512, 0, stream>>>(R1, R2, Bsw, b3, d_out, NNODES, 0);
}